// Round 1
// baseline (2730.505 us; speedup 1.0000x reference)
//
#include <hip/hip_runtime.h>

// DecoderBlock: B=4 T=1024 E=1024 H=16 D=64
// x -> LN1 -> self-MHA (+x) -> LN2 -> cross-MHA with LN2(enc) (+x) -> LN3 -> FFN (+x)
// Output: concat(x_final, encoder_embedding)
// NOTE: reference multiplies logits by sqrt(D)=8 (kept).

#define R_ROWS 4096
#define EDIM   1024
#define FDIM   4096
#define TSEQ   1024
#define NHEAD  16
#define DHEAD  64

// ---------------- LayerNorm: one block per row, 256 threads, float4 ----------------
__global__ __launch_bounds__(256) void ln_kernel(const float* __restrict__ in,
                                                 const float* __restrict__ gam,
                                                 const float* __restrict__ bet,
                                                 float* __restrict__ out) {
  const int row = blockIdx.x;
  const int tid = threadIdx.x;
  const float4* inr = (const float4*)(in + (size_t)row * EDIM);
  float4 x = inr[tid];
  float s  = x.x + x.y + x.z + x.w;
  float ss = x.x * x.x + x.y * x.y + x.z * x.z + x.w * x.w;
#pragma unroll
  for (int m = 1; m < 64; m <<= 1) {
    s  += __shfl_xor(s, m, 64);
    ss += __shfl_xor(ss, m, 64);
  }
  __shared__ float red[8];
  const int wv = tid >> 6;
  if ((tid & 63) == 0) { red[wv] = s; red[wv + 4] = ss; }
  __syncthreads();
  s  = red[0] + red[1] + red[2] + red[3];
  ss = red[4] + red[5] + red[6] + red[7];
  const float mu  = s * (1.0f / EDIM);
  const float var = ss * (1.0f / EDIM) - mu * mu;
  const float rs  = rsqrtf(var + 1e-5f);
  const float4 g4 = ((const float4*)gam)[tid];
  const float4 b4 = ((const float4*)bet)[tid];
  float4 o;
  o.x = (x.x - mu) * rs * g4.x + b4.x;
  o.y = (x.y - mu) * rs * g4.y + b4.y;
  o.z = (x.z - mu) * rs * g4.z + b4.z;
  o.w = (x.w - mu) * rs * g4.w + b4.w;
  ((float4*)(out + (size_t)row * EDIM))[tid] = o;
}

// ---------------- SGEMM: C[M,N] = A[M,K] @ B[K,N] (+bias, relu, resid) --------------
// TM x TN block tile, BK=16, 256 threads, (TM/16)x(TN/16) per-thread microtile.
template <int TM, int TN, bool BIAS, bool RELU, bool RESID>
__global__ __launch_bounds__(256) void sgemm(const float* __restrict__ A,
                                             const float* __restrict__ B,
                                             const float* __restrict__ bias,
                                             const float* __restrict__ resid,
                                             float* __restrict__ C,
                                             int M, int N, int K) {
  constexpr int BK = 16;
  constexpr int RM = TM / 16;
  constexpr int RN = TN / 16;
  constexpr int ALOADS = (TM * BK) / (256 * 4);
  constexpr int BLOADS = (TN * BK) / (256 * 4);

  __shared__ float As[BK][TM];  // transposed A tile: As[k][m]
  __shared__ float Bs[BK][TN];

  const int tid = threadIdx.x;
  const int bm = blockIdx.y * TM;
  const int bn = blockIdx.x * TN;
  const int tm = (tid >> 4) * RM;
  const int tn = (tid & 15) * RN;

  float acc[RM][RN];
#pragma unroll
  for (int i = 0; i < RM; ++i)
#pragma unroll
    for (int j = 0; j < RN; ++j) acc[i][j] = 0.0f;

  float4 areg[ALOADS], breg[BLOADS];

  for (int k0 = 0; k0 < K; k0 += BK) {
#pragma unroll
    for (int l = 0; l < ALOADS; ++l) {
      const int idx = tid + l * 256;
      const int r = idx >> 2;
      const int kc = (idx & 3) << 2;
      areg[l] = *(const float4*)&A[(size_t)(bm + r) * K + k0 + kc];
    }
#pragma unroll
    for (int l = 0; l < BLOADS; ++l) {
      const int idx = tid + l * 256;
      const int r = idx / (TN / 4);
      const int c = (idx % (TN / 4)) << 2;
      breg[l] = *(const float4*)&B[(size_t)(k0 + r) * N + bn + c];
    }
    __syncthreads();
#pragma unroll
    for (int l = 0; l < ALOADS; ++l) {
      const int idx = tid + l * 256;
      const int r = idx >> 2;
      const int kc = (idx & 3) << 2;
      As[kc + 0][r] = areg[l].x;
      As[kc + 1][r] = areg[l].y;
      As[kc + 2][r] = areg[l].z;
      As[kc + 3][r] = areg[l].w;
    }
#pragma unroll
    for (int l = 0; l < BLOADS; ++l) {
      const int idx = tid + l * 256;
      const int r = idx / (TN / 4);
      const int c = (idx % (TN / 4)) << 2;
      *(float4*)&Bs[r][c] = breg[l];
    }
    __syncthreads();

#pragma unroll
    for (int kk = 0; kk < BK; ++kk) {
      float av[RM], bv[RN];
#pragma unroll
      for (int i4 = 0; i4 < RM / 4; ++i4) {
        float4 t = *(const float4*)&As[kk][tm + 4 * i4];
        av[4 * i4 + 0] = t.x; av[4 * i4 + 1] = t.y;
        av[4 * i4 + 2] = t.z; av[4 * i4 + 3] = t.w;
      }
#pragma unroll
      for (int j4 = 0; j4 < RN / 4; ++j4) {
        float4 t = *(const float4*)&Bs[kk][tn + 4 * j4];
        bv[4 * j4 + 0] = t.x; bv[4 * j4 + 1] = t.y;
        bv[4 * j4 + 2] = t.z; bv[4 * j4 + 3] = t.w;
      }
#pragma unroll
      for (int i = 0; i < RM; ++i)
#pragma unroll
        for (int j = 0; j < RN; ++j) acc[i][j] += av[i] * bv[j];
    }
  }

  // epilogue
#pragma unroll
  for (int i = 0; i < RM; ++i) {
    const size_t row = (size_t)(bm + tm + i);
#pragma unroll
    for (int j4 = 0; j4 < RN / 4; ++j4) {
      const int col = bn + tn + 4 * j4;
      float4 o;
      o.x = acc[i][4 * j4 + 0];
      o.y = acc[i][4 * j4 + 1];
      o.z = acc[i][4 * j4 + 2];
      o.w = acc[i][4 * j4 + 3];
      if (BIAS) {
        const float4 bb = *(const float4*)&bias[col];
        o.x += bb.x; o.y += bb.y; o.z += bb.z; o.w += bb.w;
      }
      if (RELU) {
        o.x = fmaxf(o.x, 0.0f); o.y = fmaxf(o.y, 0.0f);
        o.z = fmaxf(o.z, 0.0f); o.w = fmaxf(o.w, 0.0f);
      }
      if (RESID) {
        const float4 rr = *(const float4*)&resid[row * N + col];
        o.x += rr.x; o.y += rr.y; o.z += rr.z; o.w += rr.w;
      }
      *(float4*)&C[row * N + col] = o;
    }
  }
}

// ---------------- Flash attention fp32 --------------------------------------------
// grid = (T/64, B*H). Block: 64 q-rows, loop over 16 key-tiles of 64.
// Q/K/V layout: [B*T, E] with head h at columns h*64..h*64+63.
// Threads: 16x16 grid (tr,tc); each thread: 4 q-rows x 4 cols (keys or dims).
// KVs chunk-XOR swizzle kills the 16-way bank conflict on K-column reads.
// out = resid + softmax(8 * Q K^T) V
__global__ __launch_bounds__(256) void attn_kernel(const float* __restrict__ Q,
                                                   const float* __restrict__ K,
                                                   const float* __restrict__ V,
                                                   const float* __restrict__ resid,
                                                   float* __restrict__ out) {
  __shared__ float Qs[64][68];   // padded: stride 68 -> 2-way max on reads
  __shared__ float KVs[64][64];  // swizzled float4 chunks
  __shared__ float Ps[64][68];

  const int tid = threadIdx.x;
  const int q0 = blockIdx.x * 64;
  const int bh = blockIdx.y;
  const int b = bh >> 4, h = bh & 15;
  const int tr = tid >> 4, tc = tid & 15;
  const size_t base = ((size_t)b * TSEQ) * EDIM + (size_t)h * DHEAD;

  // stage Q tile, pre-scaled by 8 (= sqrt(D) multiplier from the reference)
  {
    const int r = tid >> 2;
    const int c0 = (tid & 3) * 16;
    const float* qrow = Q + base + (size_t)(q0 + r) * EDIM + c0;
#pragma unroll
    for (int j = 0; j < 4; ++j) {
      float4 v4 = *(const float4*)(qrow + 4 * j);
      v4.x *= 8.0f; v4.y *= 8.0f; v4.z *= 8.0f; v4.w *= 8.0f;
      *(float4*)&Qs[r][c0 + 4 * j] = v4;
    }
  }

  float acc[4][4];
#pragma unroll
  for (int i = 0; i < 4; ++i)
#pragma unroll
    for (int j = 0; j < 4; ++j) acc[i][j] = 0.0f;
  float mrun[4], lrun[4];
#pragma unroll
  for (int i = 0; i < 4; ++i) { mrun[i] = -1e30f; lrun[i] = 0.0f; }

  for (int t = 0; t < 16; ++t) {
    __syncthreads();  // prev phase2 done with KVs/Ps; Qs staged on t=0
    // stage K tile (swizzled)
    {
      const int r = tid >> 2;
      const int c0q = (tid & 3) * 4;  // chunk base
      const float* krow = K + base + (size_t)(t * 64 + r) * EDIM;
      float4* dst = (float4*)&KVs[r][0];
#pragma unroll
      for (int j = 0; j < 4; ++j) {
        const float4 v4 = *(const float4*)(krow + 4 * (c0q + j));
        dst[(c0q + j) ^ (r >> 2)] = v4;
      }
    }
    __syncthreads();

    // phase 1: S = (8Q) K^T for rows 4tr.., cols 4tc..
    float s[4][4];
#pragma unroll
    for (int i = 0; i < 4; ++i)
#pragma unroll
      for (int j = 0; j < 4; ++j) s[i][j] = 0.0f;
#pragma unroll
    for (int d4 = 0; d4 < 16; ++d4) {
      float4 qv[4], kv[4];
#pragma unroll
      for (int i = 0; i < 4; ++i) qv[i] = *(const float4*)&Qs[4 * tr + i][4 * d4];
#pragma unroll
      for (int j = 0; j < 4; ++j)
        kv[j] = ((const float4*)&KVs[4 * tc + j][0])[d4 ^ tc];
#pragma unroll
      for (int i = 0; i < 4; ++i)
#pragma unroll
        for (int j = 0; j < 4; ++j)
          s[i][j] += qv[i].x * kv[j].x + qv[i].y * kv[j].y +
                     qv[i].z * kv[j].z + qv[i].w * kv[j].w;
    }

    // online softmax update (row stats across 16 lanes sharing tr)
#pragma unroll
    for (int i = 0; i < 4; ++i) {
      float mx = fmaxf(fmaxf(s[i][0], s[i][1]), fmaxf(s[i][2], s[i][3]));
      mx = fmaxf(mx, __shfl_xor(mx, 1, 64));
      mx = fmaxf(mx, __shfl_xor(mx, 2, 64));
      mx = fmaxf(mx, __shfl_xor(mx, 4, 64));
      mx = fmaxf(mx, __shfl_xor(mx, 8, 64));
      const float mnew = fmaxf(mrun[i], mx);
      const float corr = __expf(mrun[i] - mnew);
      float p0 = __expf(s[i][0] - mnew);
      float p1 = __expf(s[i][1] - mnew);
      float p2 = __expf(s[i][2] - mnew);
      float p3 = __expf(s[i][3] - mnew);
      float rs = p0 + p1 + p2 + p3;
      rs += __shfl_xor(rs, 1, 64);
      rs += __shfl_xor(rs, 2, 64);
      rs += __shfl_xor(rs, 4, 64);
      rs += __shfl_xor(rs, 8, 64);
      lrun[i] = lrun[i] * corr + rs;
      mrun[i] = mnew;
      acc[i][0] *= corr; acc[i][1] *= corr; acc[i][2] *= corr; acc[i][3] *= corr;
      float4 pv;
      pv.x = p0; pv.y = p1; pv.z = p2; pv.w = p3;
      *(float4*)&Ps[4 * tr + i][4 * tc] = pv;
    }
    __syncthreads();  // Ps visible; K reads done -> reuse KVs for V

    // stage V tile (swizzled)
    {
      const int r = tid >> 2;
      const int c0q = (tid & 3) * 4;
      const float* vrow = V + base + (size_t)(t * 64 + r) * EDIM;
      float4* dst = (float4*)&KVs[r][0];
#pragma unroll
      for (int j = 0; j < 4; ++j) {
        const float4 v4 = *(const float4*)(vrow + 4 * (c0q + j));
        dst[(c0q + j) ^ (r >> 2)] = v4;
      }
    }
    __syncthreads();

    // phase 2: acc += P V  (dims 4tc..4tc+3 for this thread)
#pragma unroll
    for (int c4 = 0; c4 < 16; ++c4) {
      float4 pv[4], vv[4];
#pragma unroll
      for (int i = 0; i < 4; ++i) pv[i] = *(const float4*)&Ps[4 * tr + i][4 * c4];
#pragma unroll
      for (int j = 0; j < 4; ++j)
        vv[j] = ((const float4*)&KVs[4 * c4 + j][0])[tc ^ c4];
#pragma unroll
      for (int i = 0; i < 4; ++i) {
        acc[i][0] += pv[i].x * vv[0].x + pv[i].y * vv[1].x + pv[i].z * vv[2].x + pv[i].w * vv[3].x;
        acc[i][1] += pv[i].x * vv[0].y + pv[i].y * vv[1].y + pv[i].z * vv[2].y + pv[i].w * vv[3].y;
        acc[i][2] += pv[i].x * vv[0].z + pv[i].y * vv[1].z + pv[i].z * vv[2].z + pv[i].w * vv[3].z;
        acc[i][3] += pv[i].x * vv[0].w + pv[i].y * vv[1].w + pv[i].z * vv[2].w + pv[i].w * vv[3].w;
      }
    }
  }

  // epilogue: normalize + residual
#pragma unroll
  for (int i = 0; i < 4; ++i) {
    const float inv = 1.0f / lrun[i];
    const size_t off = base + (size_t)(q0 + 4 * tr + i) * EDIM + 4 * tc;
    const float4 rr = *(const float4*)&resid[off];
    float4 o;
    o.x = acc[i][0] * inv + rr.x;
    o.y = acc[i][1] * inv + rr.y;
    o.z = acc[i][2] * inv + rr.z;
    o.w = acc[i][3] * inv + rr.w;
    *(float4*)&out[off] = o;
  }
}

// ---------------- launcher ---------------------------------------------------------
extern "C" void kernel_launch(void* const* d_in, const int* in_sizes, int n_in,
                              void* d_out, int out_size, void* d_ws, size_t ws_size,
                              hipStream_t stream) {
  (void)in_sizes; (void)n_in; (void)out_size; (void)ws_size;
  const float* x     = (const float*)d_in[0];
  const float* enc   = (const float*)d_in[1];
  const float* Wq_s  = (const float*)d_in[2];
  const float* Wk_s  = (const float*)d_in[3];
  const float* Wv_s  = (const float*)d_in[4];
  const float* Wq_c  = (const float*)d_in[5];
  const float* Wk_c  = (const float*)d_in[6];
  const float* Wv_c  = (const float*)d_in[7];
  const float* W1    = (const float*)d_in[8];
  const float* b1    = (const float*)d_in[9];
  const float* W2    = (const float*)d_in[10];
  const float* b2    = (const float*)d_in[11];
  const float* ln1_g = (const float*)d_in[12];
  const float* ln1_b = (const float*)d_in[13];
  const float* ln2_g = (const float*)d_in[14];
  const float* ln2_b = (const float*)d_in[15];
  const float* ln3_g = (const float*)d_in[16];
  const float* ln3_b = (const float*)d_in[17];

  float* xout = (float*)d_out;                       // evolving x lives in d_out[0:R*E]
  float* enc_out = xout + (size_t)R_ROWS * EDIM;

  // scratch: 5 buffers of R*E floats (84 MB). FFN intermediate = buf1..buf4.
  const size_t BUF = (size_t)R_ROWS * EDIM;
  float* w = (float*)d_ws;
  float* buf0 = w;
  float* buf1 = w + BUF;
  float* buf2 = w + 2 * BUF;
  float* buf3 = w + 3 * BUF;
  float* buf4 = w + 4 * BUF;
  float* ffn  = buf1;  // spans buf1..buf4 (R*F floats)

  const dim3 blk(256);
  const dim3 gLN(R_ROWS);
  const dim3 gProj(EDIM / 64, R_ROWS / 128);
  const dim3 gAttn(TSEQ / 64, 4 * NHEAD);
  const dim3 gF1(FDIM / 128, R_ROWS / 128);
  const dim3 gF2(EDIM / 64, R_ROWS / 128);

  // self-attention branch
  ln_kernel<<<gLN, blk, 0, stream>>>(x, ln1_g, ln1_b, buf0);
  sgemm<128, 64, false, false, false><<<gProj, blk, 0, stream>>>(buf0, Wq_s, nullptr, nullptr, buf1, R_ROWS, EDIM, EDIM);
  sgemm<128, 64, false, false, false><<<gProj, blk, 0, stream>>>(buf0, Wk_s, nullptr, nullptr, buf2, R_ROWS, EDIM, EDIM);
  sgemm<128, 64, false, false, false><<<gProj, blk, 0, stream>>>(buf0, Wv_s, nullptr, nullptr, buf3, R_ROWS, EDIM, EDIM);
  attn_kernel<<<gAttn, blk, 0, stream>>>(buf1, buf2, buf3, x, xout);

  // cross-attention branch
  ln_kernel<<<gLN, blk, 0, stream>>>(xout, ln2_g, ln2_b, buf4);
  ln_kernel<<<gLN, blk, 0, stream>>>(enc, ln2_g, ln2_b, buf0);
  sgemm<128, 64, false, false, false><<<gProj, blk, 0, stream>>>(buf4, Wq_c, nullptr, nullptr, buf1, R_ROWS, EDIM, EDIM);
  sgemm<128, 64, false, false, false><<<gProj, blk, 0, stream>>>(buf0, Wk_c, nullptr, nullptr, buf2, R_ROWS, EDIM, EDIM);
  sgemm<128, 64, false, false, false><<<gProj, blk, 0, stream>>>(buf0, Wv_c, nullptr, nullptr, buf3, R_ROWS, EDIM, EDIM);
  attn_kernel<<<gAttn, blk, 0, stream>>>(buf1, buf2, buf3, xout, xout);

  // FFN branch
  ln_kernel<<<gLN, blk, 0, stream>>>(xout, ln3_g, ln3_b, buf0);
  sgemm<128, 128, true, true, false><<<gF1, blk, 0, stream>>>(buf0, W1, b1, nullptr, ffn, R_ROWS, FDIM, EDIM);
  sgemm<128, 64, true, false, true><<<gF2, blk, 0, stream>>>(ffn, W2, b2, xout, xout, R_ROWS, EDIM, FDIM);

  // second tuple element: encoder_embedding passthrough
  hipMemcpyAsync(enc_out, enc, BUF * sizeof(float), hipMemcpyDeviceToDevice, stream);
}

// Round 3
// 1553.917 us; speedup vs baseline: 1.7572x; 1.7572x over previous
//
#include <hip/hip_runtime.h>

// DecoderBlock B=4 T=1024 E=1024 H=16 D=64
// Round 3 (bisect): MFMA bf16 GEMMs (split-precision hi+lo on Q/K path),
// round-1-verified fp32 flash attention, ws trimmed to 80 MB (proven size).
// NOTE: reference multiplies logits by sqrt(D)=8 (applied inside attn).

#define R_ROWS 4096
#define EDIM 1024
#define FDIM 4096
#define TSEQ 1024
#define NHEAD 16
#define DHEAD 64

typedef unsigned short u16;
typedef __attribute__((ext_vector_type(8))) short bf16x8;
typedef __attribute__((ext_vector_type(4))) float f32x4;

#define MFMA16(a, b, c) __builtin_amdgcn_mfma_f32_16x16x32_bf16((a), (b), (c), 0, 0, 0)
#define GLOAD16(g, l)                                                         \
  __builtin_amdgcn_global_load_lds(                                           \
      (const __attribute__((address_space(1))) void*)(const void*)(g),        \
      (__attribute__((address_space(3))) void*)(void*)(l), 16, 0, 0)

__device__ __forceinline__ u16 f2bf(float f) {
  union { float f; unsigned u; } c;
  c.f = f;
  unsigned r = (c.u + 0x7FFFu + ((c.u >> 16) & 1u)) >> 16;
  return (u16)r;
}
__device__ __forceinline__ float bf2f(u16 h) {
  union { unsigned u; float f; } c;
  c.u = ((unsigned)h) << 16;
  return c.f;
}

// ---------------- LayerNorm -> bf16 hi + lo ---------------------------------------
__global__ __launch_bounds__(256) void ln_kernel(const float* __restrict__ in,
                                                 const float* __restrict__ gam,
                                                 const float* __restrict__ bet,
                                                 u16* __restrict__ oh,
                                                 u16* __restrict__ ol) {
  const int row = blockIdx.x;
  const int tid = threadIdx.x;
  const float4 x = ((const float4*)(in + (size_t)row * EDIM))[tid];
  float s = x.x + x.y + x.z + x.w;
  float ss = x.x * x.x + x.y * x.y + x.z * x.z + x.w * x.w;
#pragma unroll
  for (int m = 1; m < 64; m <<= 1) {
    s += __shfl_xor(s, m, 64);
    ss += __shfl_xor(ss, m, 64);
  }
  __shared__ float red[8];
  const int wv = tid >> 6;
  if ((tid & 63) == 0) { red[wv] = s; red[wv + 4] = ss; }
  __syncthreads();
  s = red[0] + red[1] + red[2] + red[3];
  ss = red[4] + red[5] + red[6] + red[7];
  const float mu = s * (1.0f / EDIM);
  const float var = ss * (1.0f / EDIM) - mu * mu;
  const float rs = rsqrtf(var + 1e-5f);
  const float4 g4 = ((const float4*)gam)[tid];
  const float4 b4 = ((const float4*)bet)[tid];
  float v[4];
  v[0] = (x.x - mu) * rs * g4.x + b4.x;
  v[1] = (x.y - mu) * rs * g4.y + b4.y;
  v[2] = (x.z - mu) * rs * g4.z + b4.z;
  v[3] = (x.w - mu) * rs * g4.w + b4.w;
  union { u16 u[4]; uint2 w; } H, L;
#pragma unroll
  for (int j = 0; j < 4; ++j) {
    H.u[j] = f2bf(v[j]);
    L.u[j] = f2bf(v[j] - bf2f(H.u[j]));
  }
  *(uint2*)&oh[(size_t)row * EDIM + tid * 4] = H.w;
  *(uint2*)&ol[(size_t)row * EDIM + tid * 4] = L.w;
}

// ---------------- weight convert + transpose (fp32 [K][N] -> bf16 [N][K]) ---------
__global__ __launch_bounds__(256) void wcvt(const float* __restrict__ W,
                                            u16* __restrict__ oh, u16* __restrict__ ol,
                                            int K, int N) {
  __shared__ float t[32][33];
  const int tid = threadIdx.x;
  const int tx = tid & 31, ty = tid >> 5;
  const int k0 = blockIdx.x * 32, n0 = blockIdx.y * 32;
#pragma unroll
  for (int i = 0; i < 4; ++i)
    t[ty + 8 * i][tx] = W[(size_t)(k0 + ty + 8 * i) * N + n0 + tx];
  __syncthreads();
#pragma unroll
  for (int i = 0; i < 4; ++i) {
    const float v = t[tx][ty + 8 * i];
    const u16 h = f2bf(v);
    const size_t o = (size_t)(n0 + ty + 8 * i) * K + k0 + tx;
    oh[o] = h;
    if (ol) ol[o] = f2bf(v - bf2f(h));
  }
}

// ---------------- bf16 NT-GEMM: C[M,N] = A[M,K] * Bt[N,K]^T -----------------------
// m97-style: 2-barrier loop, global_load_lds(16B), source-pre-swizzled chunks.
// SPLIT: 3-pass (Ah*Bh + Ah*Bl + Al*Bh). OUT: 0=f32, 1=bf16.
template <int TM, int TN, bool SPLIT, int OUT, bool BIAS, bool RELU, bool RESID>
__global__ __launch_bounds__(256) void gemm_bf16(
    const u16* __restrict__ Ah, const u16* __restrict__ Al,
    const u16* __restrict__ Bh, const u16* __restrict__ Bl,
    const float* __restrict__ bias, const float* __restrict__ resid,
    float* __restrict__ Cf, u16* __restrict__ Ch,
    int M, int N, int K) {
  constexpr int MI = TM / 32;
  constexpr int NJ = TN / 32;
  __shared__ u16 sA[TM * 32], sB[TN * 32];
  __shared__ u16 sAl[SPLIT ? TM * 32 : 1], sBl[SPLIT ? TN * 32 : 1];

  const int tid = threadIdx.x;
  const int lane = tid & 63, wv = tid >> 6;
  const int wr = wv >> 1, wc = wv & 1;
  const int lr = lane & 15, hi = lane >> 4;
  const int bm = blockIdx.y * TM, bn = blockIdx.x * TN;

  f32x4 acc[MI][NJ];
#pragma unroll
  for (int i = 0; i < MI; ++i)
#pragma unroll
    for (int j = 0; j < NJ; ++j) acc[i][j] = (f32x4){0.f, 0.f, 0.f, 0.f};

  for (int k0 = 0; k0 < K; k0 += 32) {
    __syncthreads();
#pragma unroll
    for (int rd = 0; rd < TM / 64; ++rd) {
      const int i = rd * 256 + tid;
      const int r = i >> 2, c = i & 3;
      const int gc = c ^ ((r & 3) ^ ((r >> 2) & 3));
      const size_t go = (size_t)(bm + r) * K + k0 + gc * 8;
      GLOAD16(Ah + go, sA + (rd * 256 + wv * 64) * 8);
      if constexpr (SPLIT) GLOAD16(Al + go, sAl + (rd * 256 + wv * 64) * 8);
    }
#pragma unroll
    for (int rd = 0; rd < TN / 64; ++rd) {
      const int i = rd * 256 + tid;
      const int r = i >> 2, c = i & 3;
      const int gc = c ^ ((r & 3) ^ ((r >> 2) & 3));
      const size_t go = (size_t)(bn + r) * K + k0 + gc * 8;
      GLOAD16(Bh + go, sB + (rd * 256 + wv * 64) * 8);
      if constexpr (SPLIT) GLOAD16(Bl + go, sBl + (rd * 256 + wv * 64) * 8);
    }
    __syncthreads();

    bf16x8 af[MI], bfr[NJ];
    bf16x8 afl[SPLIT ? MI : 1], bfl[SPLIT ? NJ : 1];
#pragma unroll
    for (int mi = 0; mi < MI; ++mi) {
      const int r = wr * (TM / 2) + mi * 16 + lr;
      const int ch = hi ^ ((r & 3) ^ ((r >> 2) & 3));
      af[mi] = *(const bf16x8*)&sA[r * 32 + ch * 8];
      if constexpr (SPLIT) afl[mi] = *(const bf16x8*)&sAl[r * 32 + ch * 8];
    }
#pragma unroll
    for (int nj = 0; nj < NJ; ++nj) {
      const int r = wc * (TN / 2) + nj * 16 + lr;
      const int ch = hi ^ ((r & 3) ^ ((r >> 2) & 3));
      bfr[nj] = *(const bf16x8*)&sB[r * 32 + ch * 8];
      if constexpr (SPLIT) bfl[nj] = *(const bf16x8*)&sBl[r * 32 + ch * 8];
    }
#pragma unroll
    for (int mi = 0; mi < MI; ++mi)
#pragma unroll
      for (int nj = 0; nj < NJ; ++nj) {
        acc[mi][nj] = MFMA16(af[mi], bfr[nj], acc[mi][nj]);
        if constexpr (SPLIT) {
          acc[mi][nj] = MFMA16(af[mi], bfl[nj], acc[mi][nj]);
          acc[mi][nj] = MFMA16(afl[mi], bfr[nj], acc[mi][nj]);
        }
      }
  }

#pragma unroll
  for (int mi = 0; mi < MI; ++mi)
#pragma unroll
    for (int nj = 0; nj < NJ; ++nj) {
      const int gr = bm + wr * (TM / 2) + mi * 16 + hi * 4;
      const int gc = bn + wc * (TN / 2) + nj * 16 + lr;
      float bv = 0.f;
      if constexpr (BIAS) bv = bias[gc];
#pragma unroll
      for (int r = 0; r < 4; ++r) {
        float v = acc[mi][nj][r] + bv;
        if constexpr (RELU) v = fmaxf(v, 0.f);
        const size_t idx = (size_t)(gr + r) * N + gc;
        if constexpr (RESID) v += resid[idx];
        if constexpr (OUT == 0) {
          Cf[idx] = v;
        } else {
          Ch[idx] = f2bf(v);
        }
      }
    }
}

// ---------------- Flash attention fp32 (round-1 verified) --------------------------
__global__ __launch_bounds__(256) void attn_kernel(const float* __restrict__ Q,
                                                   const float* __restrict__ K,
                                                   const float* __restrict__ V,
                                                   const float* __restrict__ resid,
                                                   float* __restrict__ out) {
  __shared__ float Qs[64][68];
  __shared__ float KVs[64][64];
  __shared__ float Ps[64][68];

  const int tid = threadIdx.x;
  const int q0 = blockIdx.x * 64;
  const int bh = blockIdx.y;
  const int b = bh >> 4, h = bh & 15;
  const int tr = tid >> 4, tc = tid & 15;
  const size_t base = ((size_t)b * TSEQ) * EDIM + (size_t)h * DHEAD;

  {
    const int r = tid >> 2;
    const int c0 = (tid & 3) * 16;
    const float* qrow = Q + base + (size_t)(q0 + r) * EDIM + c0;
#pragma unroll
    for (int j = 0; j < 4; ++j) {
      float4 v4 = *(const float4*)(qrow + 4 * j);
      v4.x *= 8.0f; v4.y *= 8.0f; v4.z *= 8.0f; v4.w *= 8.0f;
      *(float4*)&Qs[r][c0 + 4 * j] = v4;
    }
  }

  float acc[4][4];
#pragma unroll
  for (int i = 0; i < 4; ++i)
#pragma unroll
    for (int j = 0; j < 4; ++j) acc[i][j] = 0.0f;
  float mrun[4], lrun[4];
#pragma unroll
  for (int i = 0; i < 4; ++i) { mrun[i] = -1e30f; lrun[i] = 0.0f; }

  for (int t = 0; t < 16; ++t) {
    __syncthreads();
    {
      const int r = tid >> 2;
      const int c0q = (tid & 3) * 4;
      const float* krow = K + base + (size_t)(t * 64 + r) * EDIM;
      float4* dst = (float4*)&KVs[r][0];
#pragma unroll
      for (int j = 0; j < 4; ++j) {
        const float4 v4 = *(const float4*)(krow + 4 * (c0q + j));
        dst[(c0q + j) ^ (r >> 2)] = v4;
      }
    }
    __syncthreads();

    float s[4][4];
#pragma unroll
    for (int i = 0; i < 4; ++i)
#pragma unroll
      for (int j = 0; j < 4; ++j) s[i][j] = 0.0f;
#pragma unroll
    for (int d4 = 0; d4 < 16; ++d4) {
      float4 qv[4], kv[4];
#pragma unroll
      for (int i = 0; i < 4; ++i) qv[i] = *(const float4*)&Qs[4 * tr + i][4 * d4];
#pragma unroll
      for (int j = 0; j < 4; ++j)
        kv[j] = ((const float4*)&KVs[4 * tc + j][0])[d4 ^ tc];
#pragma unroll
      for (int i = 0; i < 4; ++i)
#pragma unroll
        for (int j = 0; j < 4; ++j)
          s[i][j] += qv[i].x * kv[j].x + qv[i].y * kv[j].y +
                     qv[i].z * kv[j].z + qv[i].w * kv[j].w;
    }

#pragma unroll
    for (int i = 0; i < 4; ++i) {
      float mx = fmaxf(fmaxf(s[i][0], s[i][1]), fmaxf(s[i][2], s[i][3]));
      mx = fmaxf(mx, __shfl_xor(mx, 1, 64));
      mx = fmaxf(mx, __shfl_xor(mx, 2, 64));
      mx = fmaxf(mx, __shfl_xor(mx, 4, 64));
      mx = fmaxf(mx, __shfl_xor(mx, 8, 64));
      const float mnew = fmaxf(mrun[i], mx);
      const float corr = __expf(mrun[i] - mnew);
      float p0 = __expf(s[i][0] - mnew);
      float p1 = __expf(s[i][1] - mnew);
      float p2 = __expf(s[i][2] - mnew);
      float p3 = __expf(s[i][3] - mnew);
      float rs = p0 + p1 + p2 + p3;
      rs += __shfl_xor(rs, 1, 64);
      rs += __shfl_xor(rs, 2, 64);
      rs += __shfl_xor(rs, 4, 64);
      rs += __shfl_xor(rs, 8, 64);
      lrun[i] = lrun[i] * corr + rs;
      mrun[i] = mnew;
      acc[i][0] *= corr; acc[i][1] *= corr; acc[i][2] *= corr; acc[i][3] *= corr;
      float4 pv;
      pv.x = p0; pv.y = p1; pv.z = p2; pv.w = p3;
      *(float4*)&Ps[4 * tr + i][4 * tc] = pv;
    }
    __syncthreads();

    {
      const int r = tid >> 2;
      const int c0q = (tid & 3) * 4;
      const float* vrow = V + base + (size_t)(t * 64 + r) * EDIM;
      float4* dst = (float4*)&KVs[r][0];
#pragma unroll
      for (int j = 0; j < 4; ++j) {
        const float4 v4 = *(const float4*)(vrow + 4 * (c0q + j));
        dst[(c0q + j) ^ (r >> 2)] = v4;
      }
    }
    __syncthreads();

#pragma unroll
    for (int c4 = 0; c4 < 16; ++c4) {
      float4 pv[4], vv[4];
#pragma unroll
      for (int i = 0; i < 4; ++i) pv[i] = *(const float4*)&Ps[4 * tr + i][4 * c4];
#pragma unroll
      for (int j = 0; j < 4; ++j)
        vv[j] = ((const float4*)&KVs[4 * c4 + j][0])[tc ^ c4];
#pragma unroll
      for (int i = 0; i < 4; ++i) {
        acc[i][0] += pv[i].x * vv[0].x + pv[i].y * vv[1].x + pv[i].z * vv[2].x + pv[i].w * vv[3].x;
        acc[i][1] += pv[i].x * vv[0].y + pv[i].y * vv[1].y + pv[i].z * vv[2].y + pv[i].w * vv[3].y;
        acc[i][2] += pv[i].x * vv[0].z + pv[i].y * vv[1].z + pv[i].z * vv[2].z + pv[i].w * vv[3].z;
        acc[i][3] += pv[i].x * vv[0].w + pv[i].y * vv[1].w + pv[i].z * vv[2].w + pv[i].w * vv[3].w;
      }
    }
  }

#pragma unroll
  for (int i = 0; i < 4; ++i) {
    const float inv = 1.0f / lrun[i];
    const size_t off = base + (size_t)(q0 + 4 * tr + i) * EDIM + 4 * tc;
    const float4 rr = *(const float4*)&resid[off];
    float4 o;
    o.x = acc[i][0] * inv + rr.x;
    o.y = acc[i][1] * inv + rr.y;
    o.z = acc[i][2] * inv + rr.z;
    o.w = acc[i][3] * inv + rr.w;
    *(float4*)&out[off] = o;
  }
}

// ---------------- launcher ---------------------------------------------------------
extern "C" void kernel_launch(void* const* d_in, const int* in_sizes, int n_in,
                              void* d_out, int out_size, void* d_ws, size_t ws_size,
                              hipStream_t stream) {
  (void)in_sizes; (void)n_in; (void)out_size; (void)ws_size;
  const float* x = (const float*)d_in[0];
  const float* enc = (const float*)d_in[1];
  const float* Wq_s = (const float*)d_in[2];
  const float* Wk_s = (const float*)d_in[3];
  const float* Wv_s = (const float*)d_in[4];
  const float* Wq_c = (const float*)d_in[5];
  const float* Wk_c = (const float*)d_in[6];
  const float* Wv_c = (const float*)d_in[7];
  const float* W1 = (const float*)d_in[8];
  const float* b1 = (const float*)d_in[9];
  const float* W2 = (const float*)d_in[10];
  const float* b2 = (const float*)d_in[11];
  const float* ln1_g = (const float*)d_in[12];
  const float* ln1_b = (const float*)d_in[13];
  const float* ln2_g = (const float*)d_in[14];
  const float* ln2_b = (const float*)d_in[15];
  const float* ln3_g = (const float*)d_in[16];
  const float* ln3_b = (const float*)d_in[17];

  float* xout = (float*)d_out;
  float* enc_out = xout + (size_t)R_ROWS * EDIM;

  // ws layout (80 MB total, matches round-1-proven footprint):
  //  wbuf 16MB | lnAh 8MB | lnAl 8MB | qf 16MB | kf 16MB | vf 16MB
  char* p = (char*)d_ws;
  const size_t MB2 = (size_t)EDIM * EDIM * sizeof(u16);    // 2 MB
  const size_t ACT = (size_t)R_ROWS * EDIM * sizeof(u16);  // 8 MB
  const size_t ACF = (size_t)R_ROWS * EDIM * sizeof(float);// 16 MB
  char* wbuf = p; p += 8 * MB2;                            // 16 MB weight region
  u16* lnAh = (u16*)p; p += ACT;
  u16* lnAl = (u16*)p; p += ACT;
  float* qf = (float*)p; p += ACF;
  float* kf = (float*)p; p += ACF;
  float* vf = (float*)p; p += ACF;

  // weight views inside wbuf (attn phase: 5 x 2MB; FFN phase: 2 x 8MB)
  u16* wqh = (u16*)(wbuf + 0 * MB2);
  u16* wql = (u16*)(wbuf + 1 * MB2);
  u16* wkh = (u16*)(wbuf + 2 * MB2);
  u16* wkl = (u16*)(wbuf + 3 * MB2);
  u16* wvh = (u16*)(wbuf + 4 * MB2);
  u16* w1t = (u16*)(wbuf + 0 * MB2);                       // 8 MB
  u16* w2t = (u16*)(wbuf + 4 * MB2);                       // 8 MB
  u16* ffn = (u16*)qf;                                     // 32 MB (qf+kf), bf16

  const dim3 blk(256);
  const dim3 gW(EDIM / 32, EDIM / 32);
  const dim3 gW1(EDIM / 32, FDIM / 32);
  const dim3 gW2(FDIM / 32, EDIM / 32);
  const dim3 gLN(R_ROWS);
  const dim3 gP(EDIM / 64, R_ROWS / 128);
  const dim3 gF1(FDIM / 128, R_ROWS / 128);
  const dim3 gAttn(TSEQ / 64, 4 * NHEAD);

  // ---- self-attention branch ----
  wcvt<<<gW, blk, 0, stream>>>(Wq_s, wqh, wql, EDIM, EDIM);
  wcvt<<<gW, blk, 0, stream>>>(Wk_s, wkh, wkl, EDIM, EDIM);
  wcvt<<<gW, blk, 0, stream>>>(Wv_s, wvh, nullptr, EDIM, EDIM);
  ln_kernel<<<gLN, blk, 0, stream>>>(x, ln1_g, ln1_b, lnAh, lnAl);
  gemm_bf16<128, 64, true, 0, false, false, false><<<gP, blk, 0, stream>>>(
      lnAh, lnAl, wqh, wql, nullptr, nullptr, qf, nullptr, R_ROWS, EDIM, EDIM);
  gemm_bf16<128, 64, true, 0, false, false, false><<<gP, blk, 0, stream>>>(
      lnAh, lnAl, wkh, wkl, nullptr, nullptr, kf, nullptr, R_ROWS, EDIM, EDIM);
  gemm_bf16<128, 64, false, 0, false, false, false><<<gP, blk, 0, stream>>>(
      lnAh, nullptr, wvh, nullptr, nullptr, nullptr, vf, nullptr, R_ROWS, EDIM, EDIM);
  attn_kernel<<<gAttn, blk, 0, stream>>>(qf, kf, vf, x, xout);

  // ---- cross-attention branch (reconvert weights into same region) ----
  wcvt<<<gW, blk, 0, stream>>>(Wq_c, wqh, wql, EDIM, EDIM);
  wcvt<<<gW, blk, 0, stream>>>(Wk_c, wkh, wkl, EDIM, EDIM);
  wcvt<<<gW, blk, 0, stream>>>(Wv_c, wvh, nullptr, EDIM, EDIM);
  ln_kernel<<<gLN, blk, 0, stream>>>(xout, ln2_g, ln2_b, lnAh, lnAl);
  gemm_bf16<128, 64, true, 0, false, false, false><<<gP, blk, 0, stream>>>(
      lnAh, lnAl, wqh, wql, nullptr, nullptr, qf, nullptr, R_ROWS, EDIM, EDIM);
  ln_kernel<<<gLN, blk, 0, stream>>>(enc, ln2_g, ln2_b, lnAh, lnAl);
  gemm_bf16<128, 64, true, 0, false, false, false><<<gP, blk, 0, stream>>>(
      lnAh, lnAl, wkh, wkl, nullptr, nullptr, kf, nullptr, R_ROWS, EDIM, EDIM);
  gemm_bf16<128, 64, false, 0, false, false, false><<<gP, blk, 0, stream>>>(
      lnAh, nullptr, wvh, nullptr, nullptr, nullptr, vf, nullptr, R_ROWS, EDIM, EDIM);
  attn_kernel<<<gAttn, blk, 0, stream>>>(qf, kf, vf, xout, xout);

  // ---- FFN branch ----
  wcvt<<<gW1, blk, 0, stream>>>(W1, w1t, nullptr, EDIM, FDIM);
  wcvt<<<gW2, blk, 0, stream>>>(W2, w2t, nullptr, FDIM, EDIM);
  ln_kernel<<<gLN, blk, 0, stream>>>(xout, ln3_g, ln3_b, lnAh, lnAl);
  gemm_bf16<128, 128, false, 1, true, true, false><<<gF1, blk, 0, stream>>>(
      lnAh, nullptr, w1t, nullptr, b1, nullptr, nullptr, ffn, R_ROWS, FDIM, EDIM);
  gemm_bf16<128, 64, false, 0, true, false, true><<<gP, blk, 0, stream>>>(
      ffn, nullptr, w2t, nullptr, b2, xout, xout, nullptr, R_ROWS, EDIM, FDIM);

  // tuple element 2: encoder_embedding passthrough
  hipMemcpyAsync(enc_out, enc, (size_t)R_ROWS * EDIM * sizeof(float),
                 hipMemcpyDeviceToDevice, stream);
}

// Round 5
// 734.450 us; speedup vs baseline: 3.7178x; 2.1158x over previous
//
#include <hip/hip_runtime.h>

// DecoderBlock B=4 T=1024 E=1024 H=16 D=64 — bf16 MFMA GEMMs + MFMA flash attn.
// Q/K path split-precision (hi+lo bf16, 3-pass MFMA) for ~fp32 logits; x8 logit
// scale folded into Wq (exact pow2). V projection emits V^T so attention's PV
// uses nominal-layout operands only (no tr_b16, no inline asm). ws = 72 MB.

#define R_ROWS 4096
#define EDIM 1024
#define FDIM 4096
#define TSEQ 1024
#define NHEAD 16
#define DHEAD 64

typedef unsigned short u16;
typedef __attribute__((ext_vector_type(8))) short bf16x8;
typedef __attribute__((ext_vector_type(4))) float f32x4;

#define MFMA16(a, b, c) __builtin_amdgcn_mfma_f32_16x16x32_bf16((a), (b), (c), 0, 0, 0)
#define GLOAD16(g, l)                                                         \
  __builtin_amdgcn_global_load_lds(                                           \
      (const __attribute__((address_space(1))) void*)(const void*)(g),        \
      (__attribute__((address_space(3))) void*)(void*)(l), 16, 0, 0)

__device__ __forceinline__ u16 f2bf(float f) {
  union { float f; unsigned u; } c;
  c.f = f;
  unsigned r = (c.u + 0x7FFFu + ((c.u >> 16) & 1u)) >> 16;
  return (u16)r;
}
__device__ __forceinline__ float bf2f(u16 h) {
  union { unsigned u; float f; } c;
  c.u = ((unsigned)h) << 16;
  return c.f;
}

// ---------------- LayerNorm -> bf16 hi + lo ---------------------------------------
__global__ __launch_bounds__(256) void ln_kernel(const float* __restrict__ in,
                                                 const float* __restrict__ gam,
                                                 const float* __restrict__ bet,
                                                 u16* __restrict__ oh,
                                                 u16* __restrict__ ol) {
  const int row = blockIdx.x;
  const int tid = threadIdx.x;
  const float4 x = ((const float4*)(in + (size_t)row * EDIM))[tid];
  float s = x.x + x.y + x.z + x.w;
  float ss = x.x * x.x + x.y * x.y + x.z * x.z + x.w * x.w;
#pragma unroll
  for (int m = 1; m < 64; m <<= 1) {
    s += __shfl_xor(s, m, 64);
    ss += __shfl_xor(ss, m, 64);
  }
  __shared__ float red[8];
  const int wv = tid >> 6;
  if ((tid & 63) == 0) { red[wv] = s; red[wv + 4] = ss; }
  __syncthreads();
  s = red[0] + red[1] + red[2] + red[3];
  ss = red[4] + red[5] + red[6] + red[7];
  const float mu = s * (1.0f / EDIM);
  const float var = ss * (1.0f / EDIM) - mu * mu;
  const float rs = rsqrtf(var + 1e-5f);
  const float4 g4 = ((const float4*)gam)[tid];
  const float4 b4 = ((const float4*)bet)[tid];
  float v[4];
  v[0] = (x.x - mu) * rs * g4.x + b4.x;
  v[1] = (x.y - mu) * rs * g4.y + b4.y;
  v[2] = (x.z - mu) * rs * g4.z + b4.z;
  v[3] = (x.w - mu) * rs * g4.w + b4.w;
  union { u16 u[4]; uint2 w; } H, L;
#pragma unroll
  for (int j = 0; j < 4; ++j) {
    H.u[j] = f2bf(v[j]);
    L.u[j] = f2bf(v[j] - bf2f(H.u[j]));
  }
  *(uint2*)&oh[(size_t)row * EDIM + tid * 4] = H.w;
  *(uint2*)&ol[(size_t)row * EDIM + tid * 4] = L.w;
}

// ---------------- weight convert + transpose (fp32 [K][N] -> bf16 [N][K]) ---------
__global__ __launch_bounds__(256) void wcvt(const float* __restrict__ W,
                                            u16* __restrict__ oh, u16* __restrict__ ol,
                                            int K, int N, float scale) {
  __shared__ float t[32][33];
  const int tid = threadIdx.x;
  const int tx = tid & 31, ty = tid >> 5;
  const int k0 = blockIdx.x * 32, n0 = blockIdx.y * 32;
#pragma unroll
  for (int i = 0; i < 4; ++i)
    t[ty + 8 * i][tx] = W[(size_t)(k0 + ty + 8 * i) * N + n0 + tx] * scale;
  __syncthreads();
#pragma unroll
  for (int i = 0; i < 4; ++i) {
    const float v = t[tx][ty + 8 * i];
    const u16 h = f2bf(v);
    const size_t o = (size_t)(n0 + ty + 8 * i) * K + k0 + tx;
    oh[o] = h;
    if (ol) ol[o] = f2bf(v - bf2f(h));
  }
}

// ---------------- bf16 NT-GEMM: C[M,N] = A[M,K] * Bt[N,K]^T -----------------------
// Verified (round 3). SPLIT: 3-pass. OUT: 0=f32, 1=bf16, 2=bf16 hi+lo.
template <int TM, int TN, bool SPLIT, int OUT, bool BIAS, bool RELU, bool RESID>
__global__ __launch_bounds__(256) void gemm_bf16(
    const u16* __restrict__ Ah, const u16* __restrict__ Al,
    const u16* __restrict__ Bh, const u16* __restrict__ Bl,
    const float* __restrict__ bias, const float* __restrict__ resid,
    float* __restrict__ Cf, u16* __restrict__ Ch, u16* __restrict__ Cl,
    int M, int N, int K) {
  constexpr int MI = TM / 32;
  constexpr int NJ = TN / 32;
  __shared__ u16 sA[TM * 32], sB[TN * 32];
  __shared__ u16 sAl[SPLIT ? TM * 32 : 1], sBl[SPLIT ? TN * 32 : 1];

  const int tid = threadIdx.x;
  const int lane = tid & 63, wv = tid >> 6;
  const int wr = wv >> 1, wc = wv & 1;
  const int lr = lane & 15, hi = lane >> 4;
  const int bm = blockIdx.y * TM, bn = blockIdx.x * TN;

  f32x4 acc[MI][NJ];
#pragma unroll
  for (int i = 0; i < MI; ++i)
#pragma unroll
    for (int j = 0; j < NJ; ++j) acc[i][j] = (f32x4){0.f, 0.f, 0.f, 0.f};

  for (int k0 = 0; k0 < K; k0 += 32) {
    __syncthreads();
#pragma unroll
    for (int rd = 0; rd < TM / 64; ++rd) {
      const int i = rd * 256 + tid;
      const int r = i >> 2, c = i & 3;
      const int gc = c ^ ((r & 3) ^ ((r >> 2) & 3));
      const size_t go = (size_t)(bm + r) * K + k0 + gc * 8;
      GLOAD16(Ah + go, sA + (rd * 256 + wv * 64) * 8);
      if constexpr (SPLIT) GLOAD16(Al + go, sAl + (rd * 256 + wv * 64) * 8);
    }
#pragma unroll
    for (int rd = 0; rd < TN / 64; ++rd) {
      const int i = rd * 256 + tid;
      const int r = i >> 2, c = i & 3;
      const int gc = c ^ ((r & 3) ^ ((r >> 2) & 3));
      const size_t go = (size_t)(bn + r) * K + k0 + gc * 8;
      GLOAD16(Bh + go, sB + (rd * 256 + wv * 64) * 8);
      if constexpr (SPLIT) GLOAD16(Bl + go, sBl + (rd * 256 + wv * 64) * 8);
    }
    __syncthreads();

    bf16x8 af[MI], bfr[NJ];
    bf16x8 afl[SPLIT ? MI : 1], bfl[SPLIT ? NJ : 1];
#pragma unroll
    for (int mi = 0; mi < MI; ++mi) {
      const int r = wr * (TM / 2) + mi * 16 + lr;
      const int ch = hi ^ ((r & 3) ^ ((r >> 2) & 3));
      af[mi] = *(const bf16x8*)&sA[r * 32 + ch * 8];
      if constexpr (SPLIT) afl[mi] = *(const bf16x8*)&sAl[r * 32 + ch * 8];
    }
#pragma unroll
    for (int nj = 0; nj < NJ; ++nj) {
      const int r = wc * (TN / 2) + nj * 16 + lr;
      const int ch = hi ^ ((r & 3) ^ ((r >> 2) & 3));
      bfr[nj] = *(const bf16x8*)&sB[r * 32 + ch * 8];
      if constexpr (SPLIT) bfl[nj] = *(const bf16x8*)&sBl[r * 32 + ch * 8];
    }
#pragma unroll
    for (int mi = 0; mi < MI; ++mi)
#pragma unroll
      for (int nj = 0; nj < NJ; ++nj) {
        acc[mi][nj] = MFMA16(af[mi], bfr[nj], acc[mi][nj]);
        if constexpr (SPLIT) {
          acc[mi][nj] = MFMA16(af[mi], bfl[nj], acc[mi][nj]);
          acc[mi][nj] = MFMA16(afl[mi], bfr[nj], acc[mi][nj]);
        }
      }
  }

#pragma unroll
  for (int mi = 0; mi < MI; ++mi)
#pragma unroll
    for (int nj = 0; nj < NJ; ++nj) {
      const int gr = bm + wr * (TM / 2) + mi * 16 + hi * 4;
      const int gc = bn + wc * (TN / 2) + nj * 16 + lr;
      float bv = 0.f;
      if constexpr (BIAS) bv = bias[gc];
#pragma unroll
      for (int r = 0; r < 4; ++r) {
        float v = acc[mi][nj][r] + bv;
        if constexpr (RELU) v = fmaxf(v, 0.f);
        const size_t idx = (size_t)(gr + r) * N + gc;
        if constexpr (RESID) v += resid[idx];
        if constexpr (OUT == 0) {
          Cf[idx] = v;
        } else if constexpr (OUT == 1) {
          Ch[idx] = f2bf(v);
        } else {
          const u16 hh = f2bf(v);
          Ch[idx] = hh;
          Cl[idx] = f2bf(v - bf2f(hh));
        }
      }
    }
}

// ---------------- MFMA flash attention (nominal-layout PV, no asm) ----------------
// grid (T/64, B*H). 4 waves; wave wv owns q rows q0+wv*16..+15.
// S^T = mfma(K, Q^T) 3-pass; softmax in regs (q = lane&15); P -> per-wave LDS
// round-trip Ps[q][key] -> nominal A-fragments; V read from Vt[b][e][t] via the
// same verified swizzled-row pattern as K. out = resid + softmax(S) V.
__global__ __launch_bounds__(256) void attn_mfma(
    const u16* __restrict__ qh, const u16* __restrict__ ql,
    const u16* __restrict__ kh, const u16* __restrict__ kl,
    const u16* __restrict__ vt, const float* __restrict__ resid,
    float* __restrict__ out) {
  __shared__ u16 sKh[4096], sKl[4096], sVt[4096];
  __shared__ u16 Ps[64][72];  // [q within block][key], pad 8 -> ~2-way banks
  const int tid = threadIdx.x, lane = tid & 63, wv = tid >> 6;
  const int lr = lane & 15, hi = lane >> 4;
  const int q0 = blockIdx.x * 64, bh = blockIdx.y, b = bh >> 4, h = bh & 15;
  const int colbase = h * 64;
  const int psrow = wv * 16 + lr;

  // Q fragments in registers (B-operand of S^T): this lane's q row = q0+wv*16+lr
  bf16x8 qfh[2], qfl[2];
  {
    const size_t qoff = (size_t)(b * 1024 + q0 + wv * 16 + lr) * EDIM + colbase;
#pragma unroll
    for (int dc = 0; dc < 2; ++dc) {
      qfh[dc] = *(const bf16x8*)&qh[qoff + dc * 32 + hi * 8];
      qfl[dc] = *(const bf16x8*)&ql[qoff + dc * 32 + hi * 8];
    }
  }

  f32x4 accO[4];
#pragma unroll
  for (int m = 0; m < 4; ++m) accO[m] = (f32x4){0.f, 0.f, 0.f, 0.f};
  float mrun = -1e30f, lrun = 0.f;

  for (int t = 0; t < 16; ++t) {
    __syncthreads();
    // stage K hi/lo tiles [64 keys][64 d], 8x16B chunks/row, chunk^(row&7) swizzle
#pragma unroll
    for (int rd = 0; rd < 2; ++rd) {
      const int i = rd * 256 + tid;
      const int r = i >> 3, c = i & 7;
      const int gc = c ^ (r & 7);
      const size_t go = (size_t)(b * 1024 + t * 64 + r) * EDIM + colbase + gc * 8;
      GLOAD16(kh + go, sKh + (rd * 256 + wv * 64) * 8);
      GLOAD16(kl + go, sKl + (rd * 256 + wv * 64) * 8);
    }
    // stage Vt tile [64 d][64 keys] from Vt[b][colbase+d][t*64+key], same swizzle
#pragma unroll
    for (int rd = 0; rd < 2; ++rd) {
      const int i = rd * 256 + tid;
      const int r = i >> 3, c = i & 7;
      const int gc = c ^ (r & 7);
      const size_t gv = ((size_t)(b * 1024) + colbase + r) * 1024 + t * 64 + gc * 8;
      GLOAD16(vt + gv, sVt + (rd * 256 + wv * 64) * 8);
    }
    __syncthreads();

    // S^T[key][q], 3-pass split precision
    f32x4 accS[4];
#pragma unroll
    for (int kt = 0; kt < 4; ++kt) {
      const int r = kt * 16 + lr;
      const int c0 = (hi ^ (r & 7)) * 8;
      const int c1 = ((4 + hi) ^ (r & 7)) * 8;
      const bf16x8 a0h = *(const bf16x8*)&sKh[r * 64 + c0];
      const bf16x8 a1h = *(const bf16x8*)&sKh[r * 64 + c1];
      const bf16x8 a0l = *(const bf16x8*)&sKl[r * 64 + c0];
      const bf16x8 a1l = *(const bf16x8*)&sKl[r * 64 + c1];
      f32x4 s = (f32x4){0.f, 0.f, 0.f, 0.f};
      s = MFMA16(a0h, qfh[0], s);
      s = MFMA16(a1h, qfh[1], s);
      s = MFMA16(a0h, qfl[0], s);
      s = MFMA16(a1h, qfl[1], s);
      s = MFMA16(a0l, qfh[0], s);
      s = MFMA16(a1l, qfh[1], s);
      accS[kt] = s;
    }

    // online softmax, q = lane&15, keys kt*16 + hi*4 + r
    float mx = -1e30f;
#pragma unroll
    for (int kt = 0; kt < 4; ++kt)
#pragma unroll
      for (int r = 0; r < 4; ++r) mx = fmaxf(mx, accS[kt][r]);
    mx = fmaxf(mx, __shfl_xor(mx, 16, 64));
    mx = fmaxf(mx, __shfl_xor(mx, 32, 64));
    const float mnew = fmaxf(mrun, mx);
    const float corr = __expf(mrun - mnew);
    mrun = mnew;
    float p[16];
    float sum = 0.f;
#pragma unroll
    for (int kt = 0; kt < 4; ++kt)
#pragma unroll
      for (int r = 0; r < 4; ++r) {
        const float e = __expf(accS[kt][r] - mnew);
        p[kt * 4 + r] = e;
        sum += e;
      }
    sum += __shfl_xor(sum, 16, 64);
    sum += __shfl_xor(sum, 32, 64);
    lrun = lrun * corr + sum;
    float c4[4];
#pragma unroll
    for (int r = 0; r < 4; ++r) c4[r] = __shfl(corr, (lane & 48) | (hi * 4 + r), 64);
#pragma unroll
    for (int m = 0; m < 4; ++m)
#pragma unroll
      for (int r = 0; r < 4; ++r) accO[m][r] *= c4[r];

    // P -> LDS in [q][key] layout (per-wave rows; 4 x b64 writes)
#pragma unroll
    for (int kt = 0; kt < 4; ++kt) {
      union { u16 u[4]; uint2 w; } pk;
#pragma unroll
      for (int r = 0; r < 4; ++r) pk.u[r] = f2bf(p[kt * 4 + r]);
      *(uint2*)&Ps[psrow][kt * 16 + hi * 4] = pk.w;
    }
    // nominal A-fragments: slot (hi,j) -> key hi*8+j (+32)
    const bf16x8 pa0 = *(const bf16x8*)&Ps[psrow][hi * 8];
    const bf16x8 pa1 = *(const bf16x8*)&Ps[psrow][32 + hi * 8];

    // PV: accO[m] += P * V; B-operand from sVt rows (nominal keys via swizzle)
#pragma unroll
    for (int m = 0; m < 4; ++m) {
      const int rv = m * 16 + lr;
      const int c0v = (hi ^ (rv & 7)) * 8;
      const int c1v = ((4 + hi) ^ (rv & 7)) * 8;
      const bf16x8 vb0 = *(const bf16x8*)&sVt[rv * 64 + c0v];
      const bf16x8 vb1 = *(const bf16x8*)&sVt[rv * 64 + c1v];
      accO[m] = MFMA16(pa0, vb0, accO[m]);
      accO[m] = MFMA16(pa1, vb1, accO[m]);
    }
  }

  // epilogue: O/l + residual
  const float rinv = 1.0f / lrun;
  float i4[4];
#pragma unroll
  for (int r = 0; r < 4; ++r) i4[r] = __shfl(rinv, (lane & 48) | (hi * 4 + r), 64);
#pragma unroll
  for (int m = 0; m < 4; ++m)
#pragma unroll
    for (int r = 0; r < 4; ++r) {
      const int grow = b * 1024 + q0 + wv * 16 + hi * 4 + r;
      const size_t idx = (size_t)grow * EDIM + colbase + m * 16 + lr;
      out[idx] = accO[m][r] * i4[r] + resid[idx];
    }
}

// ---------------- launcher ---------------------------------------------------------
extern "C" void kernel_launch(void* const* d_in, const int* in_sizes, int n_in,
                              void* d_out, int out_size, void* d_ws, size_t ws_size,
                              hipStream_t stream) {
  (void)in_sizes; (void)n_in; (void)out_size; (void)ws_size;
  const float* x = (const float*)d_in[0];
  const float* enc = (const float*)d_in[1];
  const float* Wq_s = (const float*)d_in[2];
  const float* Wk_s = (const float*)d_in[3];
  const float* Wv_s = (const float*)d_in[4];
  const float* Wq_c = (const float*)d_in[5];
  const float* Wk_c = (const float*)d_in[6];
  const float* Wv_c = (const float*)d_in[7];
  const float* W1 = (const float*)d_in[8];
  const float* b1 = (const float*)d_in[9];
  const float* W2 = (const float*)d_in[10];
  const float* b2 = (const float*)d_in[11];
  const float* ln1_g = (const float*)d_in[12];
  const float* ln1_b = (const float*)d_in[13];
  const float* ln2_g = (const float*)d_in[14];
  const float* ln2_b = (const float*)d_in[15];
  const float* ln3_g = (const float*)d_in[16];
  const float* ln3_b = (const float*)d_in[17];

  float* xout = (float*)d_out;
  float* enc_out = xout + (size_t)R_ROWS * EDIM;

  // ws layout (72 MB): wbuf 16 | lnAh 8 | lnAl 8 | qh 8 | ql 8 | kh 8 | kl 8 | vt 8
  char* p = (char*)d_ws;
  const size_t MB2 = (size_t)EDIM * EDIM * sizeof(u16);    // 2 MB
  const size_t ACT = (size_t)R_ROWS * EDIM * sizeof(u16);  // 8 MB
  char* wbuf = p; p += 8 * MB2;                            // 16 MB weight region
  u16* lnAh = (u16*)p; p += ACT;
  u16* lnAl = (u16*)p; p += ACT;
  u16* qbh = (u16*)p; p += ACT;
  u16* qbl = (u16*)p; p += ACT;
  u16* kbh = (u16*)p; p += ACT;
  u16* kbl = (u16*)p; p += ACT;
  u16* vtb = (u16*)p; p += ACT;  // Vt[b][e][t]

  u16* wqh = (u16*)(wbuf + 0 * MB2);
  u16* wql = (u16*)(wbuf + 1 * MB2);
  u16* wkh = (u16*)(wbuf + 2 * MB2);
  u16* wkl = (u16*)(wbuf + 3 * MB2);
  u16* wvh = (u16*)(wbuf + 4 * MB2);
  u16* w1t = (u16*)(wbuf + 0 * MB2);   // 8 MB
  u16* w2t = (u16*)(wbuf + 4 * MB2);   // 8 MB
  u16* ffn = qbh;                      // 32 MB alias (qbh..kbl), free after attn

  const dim3 blk(256);
  const dim3 gW(EDIM / 32, EDIM / 32);
  const dim3 gW1(EDIM / 32, FDIM / 32);
  const dim3 gW2(FDIM / 32, EDIM / 32);
  const dim3 gLN(R_ROWS);
  const dim3 gP(EDIM / 64, R_ROWS / 128);
  const dim3 gVt(TSEQ / 64, EDIM / 128);   // per-batch Vt GEMM: M=E, N=T, K=E
  const dim3 gF1(FDIM / 128, R_ROWS / 128);
  const dim3 gA(TSEQ / 64, 4 * NHEAD);
  const size_t SLICE = (size_t)TSEQ * EDIM;  // elements per batch slice

  // ---- self-attention branch ----
  wcvt<<<gW, blk, 0, stream>>>(Wq_s, wqh, wql, EDIM, EDIM, 8.f);
  wcvt<<<gW, blk, 0, stream>>>(Wk_s, wkh, wkl, EDIM, EDIM, 1.f);
  wcvt<<<gW, blk, 0, stream>>>(Wv_s, wvh, nullptr, EDIM, EDIM, 1.f);
  ln_kernel<<<gLN, blk, 0, stream>>>(x, ln1_g, ln1_b, lnAh, lnAl);
  gemm_bf16<128, 64, true, 2, false, false, false><<<gP, blk, 0, stream>>>(
      lnAh, lnAl, wqh, wql, nullptr, nullptr, nullptr, qbh, qbl, R_ROWS, EDIM, EDIM);
  gemm_bf16<128, 64, true, 2, false, false, false><<<gP, blk, 0, stream>>>(
      lnAh, lnAl, wkh, wkl, nullptr, nullptr, nullptr, kbh, kbl, R_ROWS, EDIM, EDIM);
  for (int b = 0; b < 4; ++b)
    gemm_bf16<128, 64, false, 1, false, false, false><<<gVt, blk, 0, stream>>>(
        wvh, nullptr, lnAh + b * SLICE, nullptr, nullptr, nullptr, nullptr,
        vtb + b * SLICE, nullptr, EDIM, TSEQ, EDIM);
  attn_mfma<<<gA, blk, 0, stream>>>(qbh, qbl, kbh, kbl, vtb, x, xout);

  // ---- cross-attention branch (reconvert weights into same region) ----
  wcvt<<<gW, blk, 0, stream>>>(Wq_c, wqh, wql, EDIM, EDIM, 8.f);
  wcvt<<<gW, blk, 0, stream>>>(Wk_c, wkh, wkl, EDIM, EDIM, 1.f);
  wcvt<<<gW, blk, 0, stream>>>(Wv_c, wvh, nullptr, EDIM, EDIM, 1.f);
  ln_kernel<<<gLN, blk, 0, stream>>>(xout, ln2_g, ln2_b, lnAh, lnAl);
  gemm_bf16<128, 64, true, 2, false, false, false><<<gP, blk, 0, stream>>>(
      lnAh, lnAl, wqh, wql, nullptr, nullptr, nullptr, qbh, qbl, R_ROWS, EDIM, EDIM);
  ln_kernel<<<gLN, blk, 0, stream>>>(enc, ln2_g, ln2_b, lnAh, lnAl);
  gemm_bf16<128, 64, true, 2, false, false, false><<<gP, blk, 0, stream>>>(
      lnAh, lnAl, wkh, wkl, nullptr, nullptr, nullptr, kbh, kbl, R_ROWS, EDIM, EDIM);
  for (int b = 0; b < 4; ++b)
    gemm_bf16<128, 64, false, 1, false, false, false><<<gVt, blk, 0, stream>>>(
        wvh, nullptr, lnAh + b * SLICE, nullptr, nullptr, nullptr, nullptr,
        vtb + b * SLICE, nullptr, EDIM, TSEQ, EDIM);
  attn_mfma<<<gA, blk, 0, stream>>>(qbh, qbl, kbh, kbl, vtb, xout, xout);

  // ---- FFN branch ----
  wcvt<<<gW1, blk, 0, stream>>>(W1, w1t, nullptr, EDIM, FDIM, 1.f);
  wcvt<<<gW2, blk, 0, stream>>>(W2, w2t, nullptr, FDIM, EDIM, 1.f);
  ln_kernel<<<gLN, blk, 0, stream>>>(xout, ln3_g, ln3_b, lnAh, lnAl);
  gemm_bf16<128, 128, false, 1, true, true, false><<<gF1, blk, 0, stream>>>(
      lnAh, nullptr, w1t, nullptr, b1, nullptr, nullptr, ffn, nullptr, R_ROWS, FDIM, EDIM);
  gemm_bf16<128, 64, false, 0, true, false, true><<<gP, blk, 0, stream>>>(
      ffn, nullptr, w2t, nullptr, b2, xout, xout, nullptr, nullptr, R_ROWS, EDIM, FDIM);

  // tuple element 2: encoder_embedding passthrough
  hipMemcpyAsync(enc_out, enc, (size_t)R_ROWS * EDIM * sizeof(float),
                 hipMemcpyDeviceToDevice, stream);
}

// Round 7
// 707.606 us; speedup vs baseline: 3.8588x; 1.0379x over previous
//
#include <hip/hip_runtime.h>

// DecoderBlock B=4 T=1024 E=1024 H=16 D=64 — bf16 MFMA GEMMs + MFMA flash attn.
// Q/K path split-precision (hi+lo bf16, 3-pass MFMA) for ~fp32 logits; x8 logit
// scale folded into Wq (exact pow2). V projection emits V^T so attention's PV
// uses nominal-layout operands only. Round 6 resubmit (infra failure last round):
// TN=128 tiles on all big GEMMs, batched Vt GEMM via blockIdx.z. ws = 72 MB.

#define R_ROWS 4096
#define EDIM 1024
#define FDIM 4096
#define TSEQ 1024
#define NHEAD 16
#define DHEAD 64

typedef unsigned short u16;
typedef __attribute__((ext_vector_type(8))) short bf16x8;
typedef __attribute__((ext_vector_type(4))) float f32x4;

#define MFMA16(a, b, c) __builtin_amdgcn_mfma_f32_16x16x32_bf16((a), (b), (c), 0, 0, 0)
#define GLOAD16(g, l)                                                         \
  __builtin_amdgcn_global_load_lds(                                           \
      (const __attribute__((address_space(1))) void*)(const void*)(g),        \
      (__attribute__((address_space(3))) void*)(void*)(l), 16, 0, 0)

__device__ __forceinline__ u16 f2bf(float f) {
  union { float f; unsigned u; } c;
  c.f = f;
  unsigned r = (c.u + 0x7FFFu + ((c.u >> 16) & 1u)) >> 16;
  return (u16)r;
}
__device__ __forceinline__ float bf2f(u16 h) {
  union { unsigned u; float f; } c;
  c.u = ((unsigned)h) << 16;
  return c.f;
}

// ---------------- LayerNorm -> bf16 hi (+ optional lo) ----------------------------
__global__ __launch_bounds__(256) void ln_kernel(const float* __restrict__ in,
                                                 const float* __restrict__ gam,
                                                 const float* __restrict__ bet,
                                                 u16* __restrict__ oh,
                                                 u16* __restrict__ ol) {
  const int row = blockIdx.x;
  const int tid = threadIdx.x;
  const float4 x = ((const float4*)(in + (size_t)row * EDIM))[tid];
  float s = x.x + x.y + x.z + x.w;
  float ss = x.x * x.x + x.y * x.y + x.z * x.z + x.w * x.w;
#pragma unroll
  for (int m = 1; m < 64; m <<= 1) {
    s += __shfl_xor(s, m, 64);
    ss += __shfl_xor(ss, m, 64);
  }
  __shared__ float red[8];
  const int wv = tid >> 6;
  if ((tid & 63) == 0) { red[wv] = s; red[wv + 4] = ss; }
  __syncthreads();
  s = red[0] + red[1] + red[2] + red[3];
  ss = red[4] + red[5] + red[6] + red[7];
  const float mu = s * (1.0f / EDIM);
  const float var = ss * (1.0f / EDIM) - mu * mu;
  const float rs = rsqrtf(var + 1e-5f);
  const float4 g4 = ((const float4*)gam)[tid];
  const float4 b4 = ((const float4*)bet)[tid];
  float v[4];
  v[0] = (x.x - mu) * rs * g4.x + b4.x;
  v[1] = (x.y - mu) * rs * g4.y + b4.y;
  v[2] = (x.z - mu) * rs * g4.z + b4.z;
  v[3] = (x.w - mu) * rs * g4.w + b4.w;
  union { u16 u[4]; uint2 w; } H, L;
#pragma unroll
  for (int j = 0; j < 4; ++j) {
    H.u[j] = f2bf(v[j]);
    L.u[j] = f2bf(v[j] - bf2f(H.u[j]));
  }
  *(uint2*)&oh[(size_t)row * EDIM + tid * 4] = H.w;
  if (ol) *(uint2*)&ol[(size_t)row * EDIM + tid * 4] = L.w;
}

// ---------------- weight convert + transpose (fp32 [K][N] -> bf16 [N][K]) ---------
__global__ __launch_bounds__(256) void wcvt(const float* __restrict__ W,
                                            u16* __restrict__ oh, u16* __restrict__ ol,
                                            int K, int N, float scale) {
  __shared__ float t[32][33];
  const int tid = threadIdx.x;
  const int tx = tid & 31, ty = tid >> 5;
  const int k0 = blockIdx.x * 32, n0 = blockIdx.y * 32;
#pragma unroll
  for (int i = 0; i < 4; ++i)
    t[ty + 8 * i][tx] = W[(size_t)(k0 + ty + 8 * i) * N + n0 + tx] * scale;
  __syncthreads();
#pragma unroll
  for (int i = 0; i < 4; ++i) {
    const float v = t[tx][ty + 8 * i];
    const u16 h = f2bf(v);
    const size_t o = (size_t)(n0 + ty + 8 * i) * K + k0 + tx;
    oh[o] = h;
    if (ol) ol[o] = f2bf(v - bf2f(h));
  }
}

// ---------------- bf16 NT-GEMM: C[M,N] = A[M,K] * Bt[N,K]^T -----------------------
// Verified (rounds 3/5). SPLIT: 3-pass. OUT: 0=f32, 1=bf16, 2=bf16 hi+lo.
// zB/zC: per-blockIdx.z element strides on B and C (batched GEMM).
template <int TM, int TN, bool SPLIT, int OUT, bool BIAS, bool RELU, bool RESID>
__global__ __launch_bounds__(256) void gemm_bf16(
    const u16* __restrict__ Ah, const u16* __restrict__ Al,
    const u16* __restrict__ Bh, const u16* __restrict__ Bl,
    const float* __restrict__ bias, const float* __restrict__ resid,
    float* __restrict__ Cf, u16* __restrict__ Ch, u16* __restrict__ Cl,
    int M, int N, int K, size_t zB, size_t zC) {
  constexpr int MI = TM / 32;
  constexpr int NJ = TN / 32;
  __shared__ u16 sA[TM * 32], sB[TN * 32];
  __shared__ u16 sAl[SPLIT ? TM * 32 : 1], sBl[SPLIT ? TN * 32 : 1];

  const size_t zo = (size_t)blockIdx.z;
  Bh += zo * zB;
  if constexpr (SPLIT) Bl += zo * zB;
  if constexpr (OUT == 0) { Cf += zo * zC; } else { Ch += zo * zC; }

  const int tid = threadIdx.x;
  const int lane = tid & 63, wv = tid >> 6;
  const int wr = wv >> 1, wc = wv & 1;
  const int lr = lane & 15, hi = lane >> 4;
  const int bm = blockIdx.y * TM, bn = blockIdx.x * TN;

  f32x4 acc[MI][NJ];
#pragma unroll
  for (int i = 0; i < MI; ++i)
#pragma unroll
    for (int j = 0; j < NJ; ++j) acc[i][j] = (f32x4){0.f, 0.f, 0.f, 0.f};

  for (int k0 = 0; k0 < K; k0 += 32) {
    __syncthreads();
#pragma unroll
    for (int rd = 0; rd < TM / 64; ++rd) {
      const int i = rd * 256 + tid;
      const int r = i >> 2, c = i & 3;
      const int gc = c ^ ((r & 3) ^ ((r >> 2) & 3));
      const size_t go = (size_t)(bm + r) * K + k0 + gc * 8;
      GLOAD16(Ah + go, sA + (rd * 256 + wv * 64) * 8);
      if constexpr (SPLIT) GLOAD16(Al + go, sAl + (rd * 256 + wv * 64) * 8);
    }
#pragma unroll
    for (int rd = 0; rd < TN / 64; ++rd) {
      const int i = rd * 256 + tid;
      const int r = i >> 2, c = i & 3;
      const int gc = c ^ ((r & 3) ^ ((r >> 2) & 3));
      const size_t go = (size_t)(bn + r) * K + k0 + gc * 8;
      GLOAD16(Bh + go, sB + (rd * 256 + wv * 64) * 8);
      if constexpr (SPLIT) GLOAD16(Bl + go, sBl + (rd * 256 + wv * 64) * 8);
    }
    __syncthreads();

    bf16x8 af[MI], bfr[NJ];
    bf16x8 afl[SPLIT ? MI : 1], bfl[SPLIT ? NJ : 1];
#pragma unroll
    for (int mi = 0; mi < MI; ++mi) {
      const int r = wr * (TM / 2) + mi * 16 + lr;
      const int ch = hi ^ ((r & 3) ^ ((r >> 2) & 3));
      af[mi] = *(const bf16x8*)&sA[r * 32 + ch * 8];
      if constexpr (SPLIT) afl[mi] = *(const bf16x8*)&sAl[r * 32 + ch * 8];
    }
#pragma unroll
    for (int nj = 0; nj < NJ; ++nj) {
      const int r = wc * (TN / 2) + nj * 16 + lr;
      const int ch = hi ^ ((r & 3) ^ ((r >> 2) & 3));
      bfr[nj] = *(const bf16x8*)&sB[r * 32 + ch * 8];
      if constexpr (SPLIT) bfl[nj] = *(const bf16x8*)&sBl[r * 32 + ch * 8];
    }
#pragma unroll
    for (int mi = 0; mi < MI; ++mi)
#pragma unroll
      for (int nj = 0; nj < NJ; ++nj) {
        acc[mi][nj] = MFMA16(af[mi], bfr[nj], acc[mi][nj]);
        if constexpr (SPLIT) {
          acc[mi][nj] = MFMA16(af[mi], bfl[nj], acc[mi][nj]);
          acc[mi][nj] = MFMA16(afl[mi], bfr[nj], acc[mi][nj]);
        }
      }
  }

#pragma unroll
  for (int mi = 0; mi < MI; ++mi)
#pragma unroll
    for (int nj = 0; nj < NJ; ++nj) {
      const int gr = bm + wr * (TM / 2) + mi * 16 + hi * 4;
      const int gc = bn + wc * (TN / 2) + nj * 16 + lr;
      float bv = 0.f;
      if constexpr (BIAS) bv = bias[gc];
#pragma unroll
      for (int r = 0; r < 4; ++r) {
        float v = acc[mi][nj][r] + bv;
        if constexpr (RELU) v = fmaxf(v, 0.f);
        const size_t idx = (size_t)(gr + r) * N + gc;
        if constexpr (RESID) v += resid[idx];
        if constexpr (OUT == 0) {
          Cf[idx] = v;
        } else if constexpr (OUT == 1) {
          Ch[idx] = f2bf(v);
        } else {
          const u16 hh = f2bf(v);
          Ch[idx] = hh;
          Cl[idx] = f2bf(v - bf2f(hh));
        }
      }
    }
}

// ---------------- MFMA flash attention (nominal-layout PV) ------------------------
// grid (T/64, B*H). 4 waves; wave wv owns q rows q0+wv*16..+15.
// S^T = mfma(K, Q^T) 3-pass; softmax in regs (q = lane&15); P -> per-wave LDS
// round-trip Ps[q][key] -> nominal A-fragments; V read from Vt[b][e][t] via the
// same verified swizzled-row pattern as K. out = resid + softmax(S) V.
__global__ __launch_bounds__(256) void attn_mfma(
    const u16* __restrict__ qh, const u16* __restrict__ ql,
    const u16* __restrict__ kh, const u16* __restrict__ kl,
    const u16* __restrict__ vt, const float* __restrict__ resid,
    float* __restrict__ out) {
  __shared__ u16 sKh[4096], sKl[4096], sVt[4096];
  __shared__ u16 Ps[64][72];  // [q within block][key], pad 8 -> ~2-way banks
  const int tid = threadIdx.x, lane = tid & 63, wv = tid >> 6;
  const int lr = lane & 15, hi = lane >> 4;
  const int q0 = blockIdx.x * 64, bh = blockIdx.y, b = bh >> 4, h = bh & 15;
  const int colbase = h * 64;
  const int psrow = wv * 16 + lr;

  // Q fragments in registers (B-operand of S^T): this lane's q row = q0+wv*16+lr
  bf16x8 qfh[2], qfl[2];
  {
    const size_t qoff = (size_t)(b * 1024 + q0 + wv * 16 + lr) * EDIM + colbase;
#pragma unroll
    for (int dc = 0; dc < 2; ++dc) {
      qfh[dc] = *(const bf16x8*)&qh[qoff + dc * 32 + hi * 8];
      qfl[dc] = *(const bf16x8*)&ql[qoff + dc * 32 + hi * 8];
    }
  }

  f32x4 accO[4];
#pragma unroll
  for (int m = 0; m < 4; ++m) accO[m] = (f32x4){0.f, 0.f, 0.f, 0.f};
  float mrun = -1e30f, lrun = 0.f;

  for (int t = 0; t < 16; ++t) {
    __syncthreads();
    // stage K hi/lo tiles [64 keys][64 d], 8x16B chunks/row, chunk^(row&7) swizzle
#pragma unroll
    for (int rd = 0; rd < 2; ++rd) {
      const int i = rd * 256 + tid;
      const int r = i >> 3, c = i & 7;
      const int gc = c ^ (r & 7);
      const size_t go = (size_t)(b * 1024 + t * 64 + r) * EDIM + colbase + gc * 8;
      GLOAD16(kh + go, sKh + (rd * 256 + wv * 64) * 8);
      GLOAD16(kl + go, sKl + (rd * 256 + wv * 64) * 8);
    }
    // stage Vt tile [64 d][64 keys] from Vt[b][colbase+d][t*64+key], same swizzle
#pragma unroll
    for (int rd = 0; rd < 2; ++rd) {
      const int i = rd * 256 + tid;
      const int r = i >> 3, c = i & 7;
      const int gc = c ^ (r & 7);
      const size_t gv = ((size_t)(b * 1024) + colbase + r) * 1024 + t * 64 + gc * 8;
      GLOAD16(vt + gv, sVt + (rd * 256 + wv * 64) * 8);
    }
    __syncthreads();

    // S^T[key][q], 3-pass split precision
    f32x4 accS[4];
#pragma unroll
    for (int kt = 0; kt < 4; ++kt) {
      const int r = kt * 16 + lr;
      const int c0 = (hi ^ (r & 7)) * 8;
      const int c1 = ((4 + hi) ^ (r & 7)) * 8;
      const bf16x8 a0h = *(const bf16x8*)&sKh[r * 64 + c0];
      const bf16x8 a1h = *(const bf16x8*)&sKh[r * 64 + c1];
      const bf16x8 a0l = *(const bf16x8*)&sKl[r * 64 + c0];
      const bf16x8 a1l = *(const bf16x8*)&sKl[r * 64 + c1];
      f32x4 s = (f32x4){0.f, 0.f, 0.f, 0.f};
      s = MFMA16(a0h, qfh[0], s);
      s = MFMA16(a1h, qfh[1], s);
      s = MFMA16(a0h, qfl[0], s);
      s = MFMA16(a1h, qfl[1], s);
      s = MFMA16(a0l, qfh[0], s);
      s = MFMA16(a1l, qfh[1], s);
      accS[kt] = s;
    }

    // online softmax, q = lane&15, keys kt*16 + hi*4 + r
    float mx = -1e30f;
#pragma unroll
    for (int kt = 0; kt < 4; ++kt)
#pragma unroll
      for (int r = 0; r < 4; ++r) mx = fmaxf(mx, accS[kt][r]);
    mx = fmaxf(mx, __shfl_xor(mx, 16, 64));
    mx = fmaxf(mx, __shfl_xor(mx, 32, 64));
    const float mnew = fmaxf(mrun, mx);
    const float corr = __expf(mrun - mnew);
    mrun = mnew;
    float p[16];
    float sum = 0.f;
#pragma unroll
    for (int kt = 0; kt < 4; ++kt)
#pragma unroll
      for (int r = 0; r < 4; ++r) {
        const float e = __expf(accS[kt][r] - mnew);
        p[kt * 4 + r] = e;
        sum += e;
      }
    sum += __shfl_xor(sum, 16, 64);
    sum += __shfl_xor(sum, 32, 64);
    lrun = lrun * corr + sum;
    float c4[4];
#pragma unroll
    for (int r = 0; r < 4; ++r) c4[r] = __shfl(corr, (lane & 48) | (hi * 4 + r), 64);
#pragma unroll
    for (int m = 0; m < 4; ++m)
#pragma unroll
      for (int r = 0; r < 4; ++r) accO[m][r] *= c4[r];

    // P -> LDS in [q][key] layout (per-wave rows; 4 x b64 writes)
#pragma unroll
    for (int kt = 0; kt < 4; ++kt) {
      union { u16 u[4]; uint2 w; } pk;
#pragma unroll
      for (int r = 0; r < 4; ++r) pk.u[r] = f2bf(p[kt * 4 + r]);
      *(uint2*)&Ps[psrow][kt * 16 + hi * 4] = pk.w;
    }
    // nominal A-fragments: slot (hi,j) -> key hi*8+j (+32)
    const bf16x8 pa0 = *(const bf16x8*)&Ps[psrow][hi * 8];
    const bf16x8 pa1 = *(const bf16x8*)&Ps[psrow][32 + hi * 8];

    // PV: accO[m] += P * V; B-operand from sVt rows (nominal keys via swizzle)
#pragma unroll
    for (int m = 0; m < 4; ++m) {
      const int rv = m * 16 + lr;
      const int c0v = (hi ^ (rv & 7)) * 8;
      const int c1v = ((4 + hi) ^ (rv & 7)) * 8;
      const bf16x8 vb0 = *(const bf16x8*)&sVt[rv * 64 + c0v];
      const bf16x8 vb1 = *(const bf16x8*)&sVt[rv * 64 + c1v];
      accO[m] = MFMA16(pa0, vb0, accO[m]);
      accO[m] = MFMA16(pa1, vb1, accO[m]);
    }
  }

  // epilogue: O/l + residual
  const float rinv = 1.0f / lrun;
  float i4[4];
#pragma unroll
  for (int r = 0; r < 4; ++r) i4[r] = __shfl(rinv, (lane & 48) | (hi * 4 + r), 64);
#pragma unroll
  for (int m = 0; m < 4; ++m)
#pragma unroll
    for (int r = 0; r < 4; ++r) {
      const int grow = b * 1024 + q0 + wv * 16 + hi * 4 + r;
      const size_t idx = (size_t)grow * EDIM + colbase + m * 16 + lr;
      out[idx] = accO[m][r] * i4[r] + resid[idx];
    }
}

// ---------------- launcher ---------------------------------------------------------
extern "C" void kernel_launch(void* const* d_in, const int* in_sizes, int n_in,
                              void* d_out, int out_size, void* d_ws, size_t ws_size,
                              hipStream_t stream) {
  (void)in_sizes; (void)n_in; (void)out_size; (void)ws_size;
  const float* x = (const float*)d_in[0];
  const float* enc = (const float*)d_in[1];
  const float* Wq_s = (const float*)d_in[2];
  const float* Wk_s = (const float*)d_in[3];
  const float* Wv_s = (const float*)d_in[4];
  const float* Wq_c = (const float*)d_in[5];
  const float* Wk_c = (const float*)d_in[6];
  const float* Wv_c = (const float*)d_in[7];
  const float* W1 = (const float*)d_in[8];
  const float* b1 = (const float*)d_in[9];
  const float* W2 = (const float*)d_in[10];
  const float* b2 = (const float*)d_in[11];
  const float* ln1_g = (const float*)d_in[12];
  const float* ln1_b = (const float*)d_in[13];
  const float* ln2_g = (const float*)d_in[14];
  const float* ln2_b = (const float*)d_in[15];
  const float* ln3_g = (const float*)d_in[16];
  const float* ln3_b = (const float*)d_in[17];

  float* xout = (float*)d_out;
  float* enc_out = xout + (size_t)R_ROWS * EDIM;

  // ws layout (72 MB): wbuf 16 | lnAh 8 | lnAl 8 | qh 8 | ql 8 | kh 8 | kl 8 | vt 8
  char* p = (char*)d_ws;
  const size_t MB2 = (size_t)EDIM * EDIM * sizeof(u16);    // 2 MB
  const size_t ACT = (size_t)R_ROWS * EDIM * sizeof(u16);  // 8 MB
  char* wbuf = p; p += 8 * MB2;                            // 16 MB weight region
  u16* lnAh = (u16*)p; p += ACT;
  u16* lnAl = (u16*)p; p += ACT;
  u16* qbh = (u16*)p; p += ACT;
  u16* qbl = (u16*)p; p += ACT;
  u16* kbh = (u16*)p; p += ACT;
  u16* kbl = (u16*)p; p += ACT;
  u16* vtb = (u16*)p; p += ACT;  // Vt[b][e][t]

  u16* wqh = (u16*)(wbuf + 0 * MB2);
  u16* wql = (u16*)(wbuf + 1 * MB2);
  u16* wkh = (u16*)(wbuf + 2 * MB2);
  u16* wkl = (u16*)(wbuf + 3 * MB2);
  u16* wvh = (u16*)(wbuf + 4 * MB2);
  u16* w1t = (u16*)(wbuf + 0 * MB2);   // 8 MB
  u16* w2t = (u16*)(wbuf + 4 * MB2);   // 8 MB
  u16* ffn = qbh;                      // 32 MB alias (qbh..kbl), free after attn

  const dim3 blk(256);
  const dim3 gW(EDIM / 32, EDIM / 32);
  const dim3 gW1(EDIM / 32, FDIM / 32);
  const dim3 gW2(FDIM / 32, EDIM / 32);
  const dim3 gLN(R_ROWS);
  const dim3 gP(EDIM / 128, R_ROWS / 128);        // 128x128 projections / FFN2
  const dim3 gVt(TSEQ / 128, EDIM / 128, 4);      // batched Vt GEMM, z = batch
  const dim3 gF1(FDIM / 128, R_ROWS / 128);       // FFN1
  const dim3 gA(TSEQ / 64, 4 * NHEAD);
  const size_t SLICE = (size_t)TSEQ * EDIM;       // elements per batch slice

  // ---- self-attention branch ----
  wcvt<<<gW, blk, 0, stream>>>(Wq_s, wqh, wql, EDIM, EDIM, 8.f);
  wcvt<<<gW, blk, 0, stream>>>(Wk_s, wkh, wkl, EDIM, EDIM, 1.f);
  wcvt<<<gW, blk, 0, stream>>>(Wv_s, wvh, nullptr, EDIM, EDIM, 1.f);
  ln_kernel<<<gLN, blk, 0, stream>>>(x, ln1_g, ln1_b, lnAh, lnAl);
  gemm_bf16<128, 128, true, 2, false, false, false><<<gP, blk, 0, stream>>>(
      lnAh, lnAl, wqh, wql, nullptr, nullptr, nullptr, qbh, qbl, R_ROWS, EDIM, EDIM, 0, 0);
  gemm_bf16<128, 128, true, 2, false, false, false><<<gP, blk, 0, stream>>>(
      lnAh, lnAl, wkh, wkl, nullptr, nullptr, nullptr, kbh, kbl, R_ROWS, EDIM, EDIM, 0, 0);
  gemm_bf16<128, 128, false, 1, false, false, false><<<gVt, blk, 0, stream>>>(
      wvh, nullptr, lnAh, nullptr, nullptr, nullptr, nullptr, vtb, nullptr,
      EDIM, TSEQ, EDIM, SLICE, SLICE);
  attn_mfma<<<gA, blk, 0, stream>>>(qbh, qbl, kbh, kbl, vtb, x, xout);

  // ---- cross-attention branch (reconvert weights into same region) ----
  wcvt<<<gW, blk, 0, stream>>>(Wq_c, wqh, wql, EDIM, EDIM, 8.f);
  wcvt<<<gW, blk, 0, stream>>>(Wk_c, wkh, wkl, EDIM, EDIM, 1.f);
  wcvt<<<gW, blk, 0, stream>>>(Wv_c, wvh, nullptr, EDIM, EDIM, 1.f);
  ln_kernel<<<gLN, blk, 0, stream>>>(xout, ln2_g, ln2_b, lnAh, lnAl);
  gemm_bf16<128, 128, true, 2, false, false, false><<<gP, blk, 0, stream>>>(
      lnAh, lnAl, wqh, wql, nullptr, nullptr, nullptr, qbh, qbl, R_ROWS, EDIM, EDIM, 0, 0);
  ln_kernel<<<gLN, blk, 0, stream>>>(enc, ln2_g, ln2_b, lnAh, lnAl);
  gemm_bf16<128, 128, true, 2, false, false, false><<<gP, blk, 0, stream>>>(
      lnAh, lnAl, wkh, wkl, nullptr, nullptr, nullptr, kbh, kbl, R_ROWS, EDIM, EDIM, 0, 0);
  gemm_bf16<128, 128, false, 1, false, false, false><<<gVt, blk, 0, stream>>>(
      wvh, nullptr, lnAh, nullptr, nullptr, nullptr, nullptr, vtb, nullptr,
      EDIM, TSEQ, EDIM, SLICE, SLICE);
  attn_mfma<<<gA, blk, 0, stream>>>(qbh, qbl, kbh, kbl, vtb, xout, xout);

  // ---- FFN branch ----
  wcvt<<<gW1, blk, 0, stream>>>(W1, w1t, nullptr, EDIM, FDIM, 1.f);
  wcvt<<<gW2, blk, 0, stream>>>(W2, w2t, nullptr, FDIM, EDIM, 1.f);
  ln_kernel<<<gLN, blk, 0, stream>>>(xout, ln3_g, ln3_b, lnAh, nullptr);
  gemm_bf16<128, 128, false, 1, true, true, false><<<gF1, blk, 0, stream>>>(
      lnAh, nullptr, w1t, nullptr, b1, nullptr, nullptr, ffn, nullptr,
      R_ROWS, FDIM, EDIM, 0, 0);
  gemm_bf16<128, 128, false, 0, true, false, true><<<gP, blk, 0, stream>>>(
      ffn, nullptr, w2t, nullptr, b2, xout, xout, nullptr, nullptr,
      R_ROWS, EDIM, FDIM, 0, 0);

  // tuple element 2: encoder_embedding passthrough
  hipMemcpyAsync(enc_out, enc, (size_t)R_ROWS * EDIM * sizeof(float),
                 hipMemcpyDeviceToDevice, stream);
}